// Round 4
// baseline (37563.400 us; speedup 1.0000x reference)
//
#include <hip/hip_runtime.h>
#include <stdint.h>
#include <stddef.h>

// LSTMNetwork: 3-layer stacked LSTM, batch=1, T=4096, IN=64, H=1024, OUT=1.
//
// Round 12: pure per-lane dataflow. Remove ALL synchronization except the
// data dependency itself.
//   R9->R11 showed the 6us/step period is NOT probe-bandwidth (halving bytes
//   changed nothing). It is serialization shape: __all group quantization
//   (one late value => whole group re-rounds), 4-group completion, 2x
//   __syncthreads wave convoys, and LDS staging re-reads all stack LLC
//   round-trips AFTER data availability.
//   New structure (no LDS, no barriers, no __all):
//     - Every wave polls the FULL source row itself: 8 x u64 loads/lane
//       (u64 = two adjacent units, published by one producer wave as a
//       single atomic u64 store => pair validity is exact).
//     - Per-lane 8-bit pending mask; each pair is FMA'd into the 8 gate
//       accumulators the moment it is valid (straggler wait absorbed into
//       compute). Issue phase batched before check phase => ~1 LLC latency
//       per round for all pending pairs.
//     - Serial tail after last value: ~8 FMA + 17-shuffle reduce + epilogue
//       + one u64 publish.
//   Validity: fp32 with mantissa LSB stolen (stored &~1, init 0x1); all
//   buffers write-once full histories; no counters, no fences (R10 lesson).
//   Grid 640 x 256thr @ __launch_bounds__(256,3): co-resident (proven).

#define T_STEPS 4096
#define HD      1024
#define NBH     128        // h-blocks (and x-blocks) per layer

typedef unsigned long long u64;
typedef uint32_t u32;

// Module .bss (~176 MB). Harness never pokes these.
__device__ u64 g_valA[(size_t)T_STEPS * 512];   // layer0 h history, 2 units/u64 (16MB)
__device__ u64 g_valB[(size_t)T_STEPS * 512];   // layer1 h history (16MB)
__device__ u64 g_valC[(size_t)T_STEPS * 512];   // layer2 h history (16MB)
__device__ u32 g_pre1[(size_t)T_STEPS * 4096];  // layer1 gate preacts (64MB)
__device__ u32 g_pre2[(size_t)T_STEPS * 4096];  // layer2 gate preacts (64MB)

#define INITPAT 0x0000000100000001ULL

__device__ __forceinline__ float fsig(float x)  { return 1.0f / (1.0f + __expf(-x)); }
__device__ __forceinline__ float ftanh(float x) { return 1.0f - 2.0f / (__expf(2.0f * x) + 1.0f); }

__global__ __launch_bounds__(256)
void init_bufs()
{
    const size_t gtid = (size_t)blockIdx.x * blockDim.x + threadIdx.x;
    const size_t step = (size_t)gridDim.x * blockDim.x;
    const size_t nh = (size_t)T_STEPS * 512;
    const size_t np = (size_t)T_STEPS * 4096;
    for (size_t i = gtid; i < nh; i += step) { g_valA[i] = INITPAT; g_valB[i] = INITPAT; g_valC[i] = INITPAT; }
    for (size_t i = gtid; i < np; i += step) { g_pre1[i] = 1u; g_pre2[i] = 1u; }
}

__global__ __launch_bounds__(256, 3)   // 640 blocks, 3 blocks/CU cap => all co-resident
void fused_scan(const float* __restrict__ seq,
                const float* __restrict__ wih0, const float* __restrict__ whh0_,
                const float* __restrict__ bih0, const float* __restrict__ bhh0,
                const float* __restrict__ wih1, const float* __restrict__ whh1_,
                const float* __restrict__ bih1, const float* __restrict__ bhh1,
                const float* __restrict__ wih2, const float* __restrict__ whh2_,
                const float* __restrict__ bih2, const float* __restrict__ bhh2)
{
    const int bid  = blockIdx.x;
    const int lane = threadIdx.x & 63;
    const int wave = threadIdx.x >> 6;

    const bool isH  = (bid < 3 * NBH);
    const int layer = isH ? (bid >> 7) : (1 + ((bid - 3 * NBH) >> 7));
    const int bu    = isH ? (bid & (NBH - 1)) : ((bid - 3 * NBH) & (NBH - 1));
    const int j0    = bu * 8 + wave * 2;       // first of this wave's 2 units
    const int k     = lane & 7;                // acc index this lane finalizes (u*4+g)
    const int rk    = ((k & 3) << 10) + j0 + (k >> 2);   // its gate-row in [4H]

    // ---- role pointers ----
    const float* Wmat;
    const u64*  srcVal;
    u64*        valOut = nullptr;
    u32*        preOut = nullptr;
    const u32*  preIn  = nullptr;
    float       biasL  = 0.f;

    if (isH) {
        Wmat   = (layer == 0) ? whh0_ : (layer == 1) ? whh1_ : whh2_;
        valOut = (layer == 0) ? g_valA : (layer == 1) ? g_valB : g_valC;
        srcVal = valOut;                       // own history
        if (layer == 1) preIn = g_pre1;
        if (layer == 2) preIn = g_pre2;
        if (layer == 0) biasL = bih0[rk] + bhh0[rk];
    } else {
        Wmat   = (layer == 1) ? wih1 : wih2;
        srcVal = (layer == 1) ? g_valA : g_valB;
        preOut = (layer == 1) ? g_pre1 : g_pre2;
        biasL  = (layer == 1) ? (bih1[rk] + bhh1[rk]) : (bih2[rk] + bhh2[rk]);
    }

    // ---- weights into registers: 8 gate-rows x 16 elements ----
    // Element mapping for pair-dataflow: W[r][i] multiplies source element
    //   e(i) = 128*(i>>1) + 2*lane + (i&1)   (pair g = i>>1, half = i&1)
    float W[8][16];
#pragma unroll
    for (int u = 0; u < 2; ++u)
#pragma unroll
        for (int g = 0; g < 4; ++g) {
            const float* pr = Wmat + (size_t)((g << 10) + j0 + u) * HD;
#pragma unroll
            for (int i = 0; i < 16; ++i)
                W[u * 4 + g][i] = pr[((i >> 1) << 7) + (lane << 1) + (i & 1)];
        }

    float wi0[8];
    if (isH && layer == 0) {
#pragma unroll
        for (int kk = 0; kk < 8; ++kk)
            wi0[kk] = wih0[(size_t)(((kk & 3) << 10) + j0 + (kk >> 2)) * 64 + lane];
    }

    float c = 0.f;

    for (int t = 0; t < T_STEPS; ++t) {
        u32 preBits = 1u; float xv = 0.f;
        const bool needRow = (!isH) || (t > 0);

        // ---- early probes ----
        if (isH) {
            if (layer == 0) {
                xv = seq[(size_t)t * 64 + lane];
            } else {
                preBits = __hip_atomic_load(preIn + (size_t)t * 4096 + (j0 << 2) + k,
                                            __ATOMIC_RELAXED, __HIP_MEMORY_SCOPE_AGENT);
            }
        }

        // ---- accumulators (x-term for L0) ----
        float a0, a1, a2, a3, a4, a5, a6, a7;
        if (isH && layer == 0) {
            a0 = wi0[0] * xv; a1 = wi0[1] * xv; a2 = wi0[2] * xv; a3 = wi0[3] * xv;
            a4 = wi0[4] * xv; a5 = wi0[5] * xv; a6 = wi0[6] * xv; a7 = wi0[7] * xv;
        } else {
            a0 = a1 = a2 = a3 = a4 = a5 = a6 = a7 = 0.f;
        }

        // ---- per-lane dataflow poll: absorb pairs as they become valid ----
        if (needRow) {
            const u64* rp = srcVal + (size_t)(isH ? (t - 1) : t) * 512;
            u32 pend = 0xFFu;
            while (pend) {
                u64 q0, q1, q2, q3, q4, q5, q6, q7;
                // issue phase (batched; compiler overlaps the 8 loads)
                if (pend & 0x01u) q0 = __hip_atomic_load(rp + (0 << 6) + lane, __ATOMIC_RELAXED, __HIP_MEMORY_SCOPE_AGENT);
                if (pend & 0x02u) q1 = __hip_atomic_load(rp + (1 << 6) + lane, __ATOMIC_RELAXED, __HIP_MEMORY_SCOPE_AGENT);
                if (pend & 0x04u) q2 = __hip_atomic_load(rp + (2 << 6) + lane, __ATOMIC_RELAXED, __HIP_MEMORY_SCOPE_AGENT);
                if (pend & 0x08u) q3 = __hip_atomic_load(rp + (3 << 6) + lane, __ATOMIC_RELAXED, __HIP_MEMORY_SCOPE_AGENT);
                if (pend & 0x10u) q4 = __hip_atomic_load(rp + (4 << 6) + lane, __ATOMIC_RELAXED, __HIP_MEMORY_SCOPE_AGENT);
                if (pend & 0x20u) q5 = __hip_atomic_load(rp + (5 << 6) + lane, __ATOMIC_RELAXED, __HIP_MEMORY_SCOPE_AGENT);
                if (pend & 0x40u) q6 = __hip_atomic_load(rp + (6 << 6) + lane, __ATOMIC_RELAXED, __HIP_MEMORY_SCOPE_AGENT);
                if (pend & 0x80u) q7 = __hip_atomic_load(rp + (7 << 6) + lane, __ATOMIC_RELAXED, __HIP_MEMORY_SCOPE_AGENT);
                // check + absorb phase
#define ABSORB(G, Q)                                                            \
                if (pend & (1u << G)) {                                         \
                    const u32 lo = (u32)(Q), hi = (u32)((Q) >> 32);             \
                    if (!((lo | hi) & 1u)) {                                    \
                        const float h0 = __uint_as_float(lo);                   \
                        const float h1 = __uint_as_float(hi);                   \
                        a0 = __fmaf_rn(W[0][2*G+1], h1, __fmaf_rn(W[0][2*G], h0, a0)); \
                        a1 = __fmaf_rn(W[1][2*G+1], h1, __fmaf_rn(W[1][2*G], h0, a1)); \
                        a2 = __fmaf_rn(W[2][2*G+1], h1, __fmaf_rn(W[2][2*G], h0, a2)); \
                        a3 = __fmaf_rn(W[3][2*G+1], h1, __fmaf_rn(W[3][2*G], h0, a3)); \
                        a4 = __fmaf_rn(W[4][2*G+1], h1, __fmaf_rn(W[4][2*G], h0, a4)); \
                        a5 = __fmaf_rn(W[5][2*G+1], h1, __fmaf_rn(W[5][2*G], h0, a5)); \
                        a6 = __fmaf_rn(W[6][2*G+1], h1, __fmaf_rn(W[6][2*G], h0, a6)); \
                        a7 = __fmaf_rn(W[7][2*G+1], h1, __fmaf_rn(W[7][2*G], h0, a7)); \
                        pend &= ~(1u << G);                                     \
                    }                                                           \
                }
                ABSORB(0, q0) ABSORB(1, q1) ABSORB(2, q2) ABSORB(3, q3)
                ABSORB(4, q4) ABSORB(5, q5) ABSORB(6, q6) ABSORB(7, q7)
#undef ABSORB
            }
        }

        // ---- scatter-butterfly reduce: lane l ends with 64-lane sum of acc (l&7) ----
        float e;
        {
            const int l1 = lane & 1, l2 = lane & 2, l4 = lane & 4;
            const float s0 = __shfl_xor(a0, 1, 64), s1 = __shfl_xor(a1, 1, 64);
            const float s2 = __shfl_xor(a2, 1, 64), s3 = __shfl_xor(a3, 1, 64);
            const float s4 = __shfl_xor(a4, 1, 64), s5 = __shfl_xor(a5, 1, 64);
            const float s6 = __shfl_xor(a6, 1, 64), s7 = __shfl_xor(a7, 1, 64);
            const float c0 = l1 ? (a1 + s1) : (a0 + s0);
            const float c1 = l1 ? (a3 + s3) : (a2 + s2);
            const float c2 = l1 ? (a5 + s5) : (a4 + s4);
            const float c3 = l1 ? (a7 + s7) : (a6 + s6);
            const float u0 = __shfl_xor(c0, 2, 64), u1 = __shfl_xor(c1, 2, 64);
            const float u2 = __shfl_xor(c2, 2, 64), u3 = __shfl_xor(c3, 2, 64);
            const float d0 = l2 ? (c1 + u1) : (c0 + u0);
            const float d1 = l2 ? (c3 + u3) : (c2 + u2);
            const float v0 = __shfl_xor(d0, 4, 64), v1 = __shfl_xor(d1, 4, 64);
            e = l4 ? (d1 + v1) : (d0 + v0);
            e += __shfl_xor(e, 8, 64);
            e += __shfl_xor(e, 16, 64);
            e += __shfl_xor(e, 32, 64);
        }

        // ---- epilogue ----
        if (isH) {
            float add;
            if (layer == 0) {
                add = biasL;
            } else {
                while (preBits & 1u)
                    preBits = __hip_atomic_load(preIn + (size_t)t * 4096 + (j0 << 2) + k,
                                                __ATOMIC_RELAXED, __HIP_MEMORY_SCOPE_AGENT);
                add = __uint_as_float(preBits);   // preact carries Wih.x + b_ih + b_hh
            }
            const float val = e + add;
            // gate nonlinearity: k&3 == 2 is the g-gate (tanh), others sigmoid
            const float av = ((lane & 3) == 2) ? ftanh(val) : fsig(val);
            const int gb = lane & ~3;
            const float iv = __shfl(av, gb + 0, 64);
            const float fv = __shfl(av, gb + 1, 64);
            const float gv = __shfl(av, gb + 2, 64);
            const float ov = __shfl(av, gb + 3, 64);
            c = __fmaf_rn(fv, c, iv * gv);
            const float h = ov * ftanh(c);
            const float hHi = __shfl(h, 4, 64);   // unit j0+1's h (lanes 4..7 replica)
            if (lane == 0) {
                const u64 pk = ((u64)(__float_as_uint(hHi) & ~1u) << 32)
                             | (u64)(__float_as_uint(h) & ~1u);
                __hip_atomic_store(valOut + (size_t)t * 512 + (j0 >> 1), pk,
                                   __ATOMIC_RELAXED, __HIP_MEMORY_SCOPE_AGENT);
            }
        } else {
            const float val = e + biasL;
            if (lane < 8)
                __hip_atomic_store(preOut + (size_t)t * 4096 + (j0 << 2) + lane,
                                   __float_as_uint(val) & ~1u,
                                   __ATOMIC_RELAXED, __HIP_MEMORY_SCOPE_AGENT);
        }
    }
}

__global__ __launch_bounds__(256)
void final_kernel(const float* __restrict__ w_lin,
                  const float* __restrict__ b_lin,
                  float*       __restrict__ out)
{
    __shared__ float red[256];
    const int tid = threadIdx.x;
    const u64* vrow = g_valC + (size_t)(T_STEPS - 1) * 512;
    float s = 0.f;
#pragma unroll
    for (int i = 0; i < 2; ++i) {
        const int d = tid * 2 + i;               // u64 index -> units 2d, 2d+1
        const u64 q = vrow[d];
        s += __uint_as_float((u32)q)         * w_lin[2 * d]
           + __uint_as_float((u32)(q >> 32)) * w_lin[2 * d + 1];
    }
    red[tid] = s;
    __syncthreads();
    for (int o = 128; o > 0; o >>= 1) {
        if (tid < o) red[tid] += red[tid + o];
        __syncthreads();
    }
    if (tid == 0) out[0] = red[0] + b_lin[0];
}

extern "C" void kernel_launch(void* const* d_in, const int* in_sizes, int n_in,
                              void* d_out, int out_size, void* d_ws, size_t ws_size,
                              hipStream_t stream)
{
    (void)in_sizes; (void)n_in; (void)out_size; (void)d_ws; (void)ws_size;

    const float* seq   = (const float*)d_in[0];
    const float* w_ih0 = (const float*)d_in[1];
    const float* w_hh0 = (const float*)d_in[2];
    const float* b_ih0 = (const float*)d_in[3];
    const float* b_hh0 = (const float*)d_in[4];
    const float* w_ih1 = (const float*)d_in[5];
    const float* w_hh1 = (const float*)d_in[6];
    const float* b_ih1 = (const float*)d_in[7];
    const float* b_hh1 = (const float*)d_in[8];
    const float* w_ih2 = (const float*)d_in[9];
    const float* w_hh2 = (const float*)d_in[10];
    const float* b_ih2 = (const float*)d_in[11];
    const float* b_hh2 = (const float*)d_in[12];
    const float* w_lin = (const float*)d_in[13];
    const float* b_lin = (const float*)d_in[14];

    // Replay hygiene: all slots back to "unwritten" (LSB=1) each launch.
    init_bufs<<<dim3(2048), dim3(256), 0, stream>>>();

    // Blocks [0,384) = h-role (128/layer); [384,640) = x-role (128 for L1, 128 for L2).
    fused_scan<<<dim3(640), dim3(256), 0, stream>>>(
        seq,
        w_ih0, w_hh0, b_ih0, b_hh0,
        w_ih1, w_hh1, b_ih1, b_hh1,
        w_ih2, w_hh2, b_ih2, b_hh2);

    final_kernel<<<dim3(1), dim3(256), 0, stream>>>(w_lin, b_lin, (float*)d_out);
}